// Round 4
// baseline (731.295 us; speedup 1.0000x reference)
//
#include <hip/hip_runtime.h>
#include <hip/hip_bf16.h>
#include <hip/hip_fp16.h>

#define N_NODES 40000
#define N_EDGES 300000
#define EMBED 256
#define CAP 64              // max in-degree per (node,dir); Poisson(7.5) tail => safe

typedef __attribute__((ext_vector_type(8))) short s16x8;   // 8 bf16 (4 VGPRs)
typedef __attribute__((ext_vector_type(4))) float f32x4;   // 4 fp32
typedef __attribute__((ext_vector_type(2))) unsigned int u32x2; // 8B (2 VGPRs)

__device__ __forceinline__ unsigned short f2b(float f) {   // fp32 -> bf16 RNE
    unsigned int x = __float_as_uint(f);
    x += 0x7fffu + ((x >> 16) & 1u);
    return (unsigned short)(x >> 16);
}
// int64 layout sniff (odd int32 words all zero) — insurance, contract says int32
__device__ __forceinline__ bool ht_is_i64(const int* __restrict__ ht) {
    int o = 0;
    #pragma unroll
    for (int k = 1; k < 16; k += 2) o |= ht[k];
    return o == 0;
}
__device__ __forceinline__ int clampN(int v) {
    unsigned u = (unsigned)v;
    return (u < N_NODES) ? v : 0;
}

template<bool EF16> struct EVT;
template<> struct EVT<true>  { using T = u32x2; };   // 4 x f16 (8B)
template<> struct EVT<false> { using T = f32x4; };   // 4 x f32 (16B)

// ---- fp32 -> bf16: H -> Hbf; Wf|Wb -> Wcat; optionally E -> Ef (fp16) ------
template<bool EF16>
__global__ __launch_bounds__(256) void convert_kernel(
    const float* __restrict__ H, const float* __restrict__ Wf,
    const float* __restrict__ Wb, const float* __restrict__ E,
    unsigned short* __restrict__ Hbf, unsigned short* __restrict__ Wcat,
    unsigned short* __restrict__ Ef)
{
    constexpr int NH4 = (N_NODES * EMBED) / 4;     // 2,560,000
    constexpr int NW4 = (EMBED * 2 * EMBED) / 4;   // 32,768 per W
    constexpr int NE4 = (N_EDGES * EMBED) / 4;     // 19,200,000
    int ci = blockIdx.x * 256 + threadIdx.x;
    if (ci < NH4) {
        float4 v = *(const float4*)&H[(size_t)ci * 4];
        ushort4 o; o.x=f2b(v.x); o.y=f2b(v.y); o.z=f2b(v.z); o.w=f2b(v.w);
        *(ushort4*)&Hbf[(size_t)ci * 4] = o;
    } else if (ci < NH4 + NW4) {
        int j = (ci - NH4) * 4; int n = j >> 9, k = j & 511;
        float4 v = *(const float4*)&Wf[j];
        ushort4 o; o.x=f2b(v.x); o.y=f2b(v.y); o.z=f2b(v.z); o.w=f2b(v.w);
        *(ushort4*)&Wcat[(size_t)n * 1024 + k] = o;
    } else if (ci < NH4 + 2 * NW4) {
        int j = (ci - NH4 - NW4) * 4; int n = j >> 9, k = j & 511;
        float4 v = *(const float4*)&Wb[j];
        ushort4 o; o.x=f2b(v.x); o.y=f2b(v.y); o.z=f2b(v.z); o.w=f2b(v.w);
        *(ushort4*)&Wcat[(size_t)n * 1024 + 512 + k] = o;
    } else if (EF16 && ci < NH4 + 2 * NW4 + NE4) {
        size_t j = (size_t)(ci - NH4 - 2 * NW4) * 4;
        float4 v = *(const float4*)&E[j];
        ushort4 o;
        o.x = __half_as_ushort(__float2half(v.x));
        o.y = __half_as_ushort(__float2half(v.y));
        o.z = __half_as_ushort(__float2half(v.z));
        o.w = __half_as_ushort(__float2half(v.w));
        *(ushort4*)&Ef[j] = o;
    }
}

// ---- build padded per-node edge lists (fwd keyed by tail, back by head) ----
__global__ __launch_bounds__(256) void build_kernel(
    const int* __restrict__ ht,
    int* __restrict__ cntf, int* __restrict__ cntb,
    int* __restrict__ listf, int* __restrict__ listb)
{
    int e = blockIdx.x * 256 + threadIdx.x;
    if (e >= N_EDGES) return;
    const bool wide = ht_is_i64(ht);
    int head = clampN(wide ? ht[(size_t)4 * e]     : ht[2 * e]);
    int tail = clampN(wide ? ht[(size_t)4 * e + 2] : ht[2 * e + 1]);
    int pf = atomicAdd(&cntf[tail], 1);
    if (pf < CAP) listf[tail * CAP + pf] = e;
    int pb = atomicAdd(&cntb[head], 1);
    if (pb < CAP) listb[head * CAP + pb] = e;
}

// One node's full gather: fwd+back issued together (32 loads in flight),
// counted drain vmcnt(16) -> consume fwd -> vmcnt(0) -> consume back.
template<bool EF16>
__device__ __forceinline__ void gather_node(
    const void* __restrict__ Ep, const unsigned short* __restrict__ Hbf,
    int eFr, int nFr, int eBr, int nBr, int ncF, int ncB, int lane,
    float (&aHf)[4], float (&aEf)[4], float (&aHb)[4], float (&aEb)[4])
{
    using EV = typename EVT<EF16>::T;
    const int nmax = (ncF > ncB) ? ncF : ncB;
    for (int t = 0; t < nmax; t += 8) {
        EV evf[8], evb[8]; u32x2 hvf[8], hvb[8];
        #pragma unroll
        for (int u = 0; u < 8; u++) {
            const int e_  = __builtin_amdgcn_readlane(eFr, t + u);
            const int nb_ = __builtin_amdgcn_readlane(nFr, t + u);
            const unsigned short* ph = Hbf + (size_t)nb_ * EMBED + lane * 4;
            if constexpr (EF16) {
                const unsigned short* pe = (const unsigned short*)Ep + (size_t)e_ * EMBED + lane * 4;
                asm volatile("global_load_dwordx2 %0, %1, off" : "=v"(evf[u]) : "v"(pe));
            } else {
                const float* pe = (const float*)Ep + (size_t)e_ * EMBED + lane * 4;
                asm volatile("global_load_dwordx4 %0, %1, off" : "=v"(evf[u]) : "v"(pe));
            }
            asm volatile("global_load_dwordx2 %0, %1, off" : "=v"(hvf[u]) : "v"(ph));
        }
        #pragma unroll
        for (int u = 0; u < 8; u++) {
            const int e_  = __builtin_amdgcn_readlane(eBr, t + u);
            const int nb_ = __builtin_amdgcn_readlane(nBr, t + u);
            const unsigned short* ph = Hbf + (size_t)nb_ * EMBED + lane * 4;
            if constexpr (EF16) {
                const unsigned short* pe = (const unsigned short*)Ep + (size_t)e_ * EMBED + lane * 4;
                asm volatile("global_load_dwordx2 %0, %1, off" : "=v"(evb[u]) : "v"(pe));
            } else {
                const float* pe = (const float*)Ep + (size_t)e_ * EMBED + lane * 4;
                asm volatile("global_load_dwordx4 %0, %1, off" : "=v"(evb[u]) : "v"(pe));
            }
            asm volatile("global_load_dwordx2 %0, %1, off" : "=v"(hvb[u]) : "v"(ph));
        }
        asm volatile("s_waitcnt vmcnt(16)" ::: "memory");   // fwd 16 complete
        __builtin_amdgcn_sched_barrier(0);
        #pragma unroll
        for (int u = 0; u < 8; u++) {
            const float w = (t + u < ncF) ? 1.0f : 0.0f;
            if constexpr (EF16) {
                aEf[0] += w * __half2float(__ushort_as_half((unsigned short)(evf[u].x & 0xffffu)));
                aEf[1] += w * __half2float(__ushort_as_half((unsigned short)(evf[u].x >> 16)));
                aEf[2] += w * __half2float(__ushort_as_half((unsigned short)(evf[u].y & 0xffffu)));
                aEf[3] += w * __half2float(__ushort_as_half((unsigned short)(evf[u].y >> 16)));
            } else {
                aEf[0] += w * evf[u].x; aEf[1] += w * evf[u].y;
                aEf[2] += w * evf[u].z; aEf[3] += w * evf[u].w;
            }
            aHf[0] += w * __uint_as_float(hvf[u].x << 16);
            aHf[1] += w * __uint_as_float(hvf[u].x & 0xffff0000u);
            aHf[2] += w * __uint_as_float(hvf[u].y << 16);
            aHf[3] += w * __uint_as_float(hvf[u].y & 0xffff0000u);
        }
        asm volatile("s_waitcnt vmcnt(0)" ::: "memory");    // back 16 complete
        __builtin_amdgcn_sched_barrier(0);
        #pragma unroll
        for (int u = 0; u < 8; u++) {
            const float w = (t + u < ncB) ? 1.0f : 0.0f;
            if constexpr (EF16) {
                aEb[0] += w * __half2float(__ushort_as_half((unsigned short)(evb[u].x & 0xffffu)));
                aEb[1] += w * __half2float(__ushort_as_half((unsigned short)(evb[u].x >> 16)));
                aEb[2] += w * __half2float(__ushort_as_half((unsigned short)(evb[u].y & 0xffffu)));
                aEb[3] += w * __half2float(__ushort_as_half((unsigned short)(evb[u].y >> 16)));
            } else {
                aEb[0] += w * evb[u].x; aEb[1] += w * evb[u].y;
                aEb[2] += w * evb[u].z; aEb[3] += w * evb[u].w;
            }
            aHb[0] += w * __uint_as_float(hvb[u].x << 16);
            aHb[1] += w * __uint_as_float(hvb[u].x & 0xffff0000u);
            aHb[2] += w * __uint_as_float(hvb[u].y << 16);
            aHb[3] += w * __uint_as_float(hvb[u].y & 0xffff0000u);
        }
    }
}

// ---- fused: gather-sum S (LDS, bf16) -> GEMM vs Wcat -> bias/mean/leaky/
// ---- residual/LayerNorm -> out. Block = 16 nodes, 256 thr (4 waves).
template<bool EF16>
__global__ __launch_bounds__(256, 2) void fused_kernel(
    const unsigned short* __restrict__ Hbf, const void* __restrict__ Ep,
    const int* __restrict__ ht, const unsigned short* __restrict__ Wcat,
    const float* __restrict__ bf_, const float* __restrict__ bb_,
    const float* __restrict__ H, const float* __restrict__ lw,
    const float* __restrict__ lb,
    const int* __restrict__ cntf, const int* __restrict__ cntb,
    const int* __restrict__ listf, const int* __restrict__ listb,
    float* __restrict__ out)
{
    constexpr int LDK = 1032;                 // 1024 + 8 pad (keeps 16B align)
    __shared__ unsigned short S[16 * LDK];    // 33 KB
    __shared__ float stats[16][4][2];         // per-row per-wave (s, ss)

    const int tid  = threadIdx.x;
    const int wid  = tid >> 6;
    const int lane = tid & 63;
    const int q    = lane >> 4;
    const int c    = lane & 15;
    const int m0   = blockIdx.x * 16;
    const bool wide = ht_is_i64(ht);

    // ---- hoisted preloads: counts + edge lists + neighbor ids, 4 nodes/wave.
    int cF[4], cB[4];
    int eF[4], eB[4], nF[4], nB[4];
    #pragma unroll
    for (int i = 0; i < 4; i++) {
        const int node = m0 + wid * 4 + i;
        cF[i] = min(cntf[node], CAP);
        cB[i] = min(cntb[node], CAP);
    }
    #pragma unroll
    for (int i = 0; i < 4; i++) {
        const int node = m0 + wid * 4 + i;
        eF[i] = (lane < cF[i]) ? listf[node * CAP + lane] : 0;
        eB[i] = (lane < cB[i]) ? listb[node * CAP + lane] : 0;
    }
    #pragma unroll
    for (int i = 0; i < 4; i++) {
        nF[i] = clampN(wide ? ht[(size_t)4 * eF[i]]     : ht[2 * eF[i]]);      // head
        nB[i] = clampN(wide ? ht[(size_t)4 * eB[i] + 2] : ht[2 * eB[i] + 1]);  // tail
    }

    const int loff = lane * 4;

    // ---- gather phase: wave owns 4 nodes; 32-load merged fwd/back batches --
    #pragma unroll
    for (int i = 0; i < 4; i++) {
        const int r = wid * 4 + i;
        float aHf[4] = {0.f,0.f,0.f,0.f}, aEf[4] = {0.f,0.f,0.f,0.f};
        float aHb[4] = {0.f,0.f,0.f,0.f}, aEb[4] = {0.f,0.f,0.f,0.f};

        const int ncF = __builtin_amdgcn_readfirstlane(cF[i]);  // wave-uniform
        const int ncB = __builtin_amdgcn_readfirstlane(cB[i]);
        gather_node<EF16>(Ep, Hbf, eF[i], nF[i], eB[i], nB[i], ncF, ncB, lane,
                          aHf, aEf, aHb, aEb);

        // S row r = [ΣH_head | ΣE_fwd | ΣH_tail | ΣE_back] as bf16
        ushort4 o;
        o.x=f2b(aHf[0]); o.y=f2b(aHf[1]); o.z=f2b(aHf[2]); o.w=f2b(aHf[3]);
        *(ushort4*)(&S[r * LDK +   0 + loff]) = o;
        o.x=f2b(aEf[0]); o.y=f2b(aEf[1]); o.z=f2b(aEf[2]); o.w=f2b(aEf[3]);
        *(ushort4*)(&S[r * LDK + 256 + loff]) = o;
        o.x=f2b(aHb[0]); o.y=f2b(aHb[1]); o.z=f2b(aHb[2]); o.w=f2b(aHb[3]);
        *(ushort4*)(&S[r * LDK + 512 + loff]) = o;
        o.x=f2b(aEb[0]); o.y=f2b(aEb[1]); o.z=f2b(aEb[2]); o.w=f2b(aEb[3]);
        *(ushort4*)(&S[r * LDK + 768 + loff]) = o;
    }
    __syncthreads();

    // ---- GEMM: 16 x 1024 x 256, wave covers cols n0..n0+63 ----------------
    const int n0 = wid * 64;
    f32x4 acc[4];
    #pragma unroll
    for (int nt = 0; nt < 4; nt++) acc[nt] = (f32x4){0.f,0.f,0.f,0.f};

    #pragma unroll 4
    for (int k0 = 0; k0 < 1024; k0 += 32) {
        // A frag: A[m=c][k=q*8+j]
        s16x8 a = *(const s16x8*)(&S[c * LDK + k0 + q * 8]);
        #pragma unroll
        for (int nt = 0; nt < 4; nt++) {
            s16x8 b = *(const s16x8*)(&Wcat[(size_t)(n0 + nt * 16 + c) * 1024 + k0 + q * 8]);
            acc[nt] = __builtin_amdgcn_mfma_f32_16x16x32_bf16(a, b, acc[nt], 0, 0, 0);
        }
    }

    // ---- epilogue: bias, /count, leaky, +H, LayerNorm ----------------------
    float x[4][4];                 // [reg(row)][nt]
    float sr[4], ssr[4];
    #pragma unroll
    for (int reg = 0; reg < 4; reg++) {
        const int row  = q * 4 + reg;
        const int node = m0 + row;
        const float cf = (float)cntf[node];
        const float cb = (float)cntb[node];
        const float tot = cf + cb;
        const float inv = (tot > 0.f) ? (1.0f / tot) : 0.f;
        float s = 0.f, ss = 0.f;
        #pragma unroll
        for (int nt = 0; nt < 4; nt++) {
            const int j = n0 + nt * 16 + c;
            float v = acc[nt][reg] + cf * bf_[j] + cb * bb_[j];
            float m = v * inv;
            m = (m > 0.f) ? m : 0.01f * m;          // leaky_relu
            float xx = m + H[(size_t)node * EMBED + j];
            x[reg][nt] = xx; s += xx; ss += xx * xx;
        }
        sr[reg] = s; ssr[reg] = ss;
    }
    // reduce over the 16 c-lanes within each quad
    #pragma unroll
    for (int off = 1; off < 16; off <<= 1) {
        #pragma unroll
        for (int reg = 0; reg < 4; reg++) {
            sr[reg]  += __shfl_xor(sr[reg],  off);
            ssr[reg] += __shfl_xor(ssr[reg], off);
        }
    }
    if (c == 0) {
        #pragma unroll
        for (int reg = 0; reg < 4; reg++) {
            stats[q * 4 + reg][wid][0] = sr[reg];
            stats[q * 4 + reg][wid][1] = ssr[reg];
        }
    }
    __syncthreads();
    #pragma unroll
    for (int reg = 0; reg < 4; reg++) {
        const int row  = q * 4 + reg;
        const int node = m0 + row;
        float s  = stats[row][0][0] + stats[row][1][0] + stats[row][2][0] + stats[row][3][0];
        float ss = stats[row][0][1] + stats[row][1][1] + stats[row][2][1] + stats[row][3][1];
        const float mean = s * (1.0f / EMBED);
        float var = ss * (1.0f / EMBED) - mean * mean;
        var = var < 0.f ? 0.f : var;
        const float rstd = rsqrtf(var + 1e-5f);
        #pragma unroll
        for (int nt = 0; nt < 4; nt++) {
            const int j = n0 + nt * 16 + c;
            out[(size_t)node * EMBED + j] = (x[reg][nt] - mean) * rstd * lw[j] + lb[j];
        }
    }
}

extern "C" void kernel_launch(void* const* d_in, const int* in_sizes, int n_in,
                              void* d_out, int out_size, void* d_ws, size_t ws_size,
                              hipStream_t stream) {
    const float* H   = (const float*)d_in[0];
    const float* E   = (const float*)d_in[1];
    const int*   ht  = (const int*)d_in[2];
    const float* Wf  = (const float*)d_in[5];
    const float* bf_ = (const float*)d_in[6];
    const float* Wb  = (const float*)d_in[7];
    const float* bb_ = (const float*)d_in[8];
    const float* lw  = (const float*)d_in[9];
    const float* lb  = (const float*)d_in[10];
    float* out = (float*)d_out;

    // ws layout: counters, lists, Hbf, Wcat, [Ef16 if room]
    int* cntf  = (int*)d_ws;                       // 40960 ints
    int* cntb  = cntf + 40960;
    int* listf = cntb + 40960;                     // 40000*CAP ints
    int* listb = listf + N_NODES * CAP;
    unsigned short* Hbf  = (unsigned short*)(listb + N_NODES * CAP);  // 10.24M
    unsigned short* Wcat = Hbf + (size_t)N_NODES * EMBED;             // 262144
    unsigned short* Ef   = Wcat + (size_t)256 * 1024;                 // 76.8M shorts

    const size_t need_base = (size_t)(2 * 40960) * 4 + (size_t)2 * N_NODES * CAP * 4
                           + ((size_t)N_NODES * EMBED + (size_t)256 * 1024) * 2;
    const size_t need_ef16 = need_base + (size_t)N_EDGES * EMBED * 2;
    const bool ef16 = (ws_size >= need_ef16);

    hipMemsetAsync(d_ws, 0, 2 * 40960 * sizeof(int), stream);

    constexpr int NBASE = (N_NODES * EMBED + 2 * EMBED * 2 * EMBED) / 4;
    constexpr int NEXT  = NBASE + (N_EDGES * EMBED) / 4;
    if (ef16) {
        convert_kernel<true><<<(NEXT + 255) / 256, 256, 0, stream>>>(
            H, Wf, Wb, E, Hbf, Wcat, Ef);
    } else {
        convert_kernel<false><<<(NBASE + 255) / 256, 256, 0, stream>>>(
            H, Wf, Wb, E, Hbf, Wcat, Ef);
    }
    build_kernel<<<(N_EDGES + 255) / 256, 256, 0, stream>>>(ht, cntf, cntb, listf, listb);
    if (ef16) {
        fused_kernel<true><<<N_NODES / 16, 256, 0, stream>>>(
            Hbf, (const void*)Ef, ht, Wcat, bf_, bb_, H, lw, lb,
            cntf, cntb, listf, listb, out);
    } else {
        fused_kernel<false><<<N_NODES / 16, 256, 0, stream>>>(
            Hbf, (const void*)E, ht, Wcat, bf_, bb_, H, lw, lb,
            cntf, cntb, listf, listb, out);
    }
}

// Round 6
// 691.169 us; speedup vs baseline: 1.0581x; 1.0581x over previous
//
#include <hip/hip_runtime.h>
#include <hip/hip_bf16.h>

#define N_NODES 40000
#define N_EDGES 300000
#define EMBED 256
#define CAP 64              // max in-degree per (node,dir); Poisson(7.5) tail => safe

typedef __attribute__((ext_vector_type(8))) short s16x8;   // 8 bf16 (4 VGPRs)
typedef __attribute__((ext_vector_type(4))) float f32x4;   // 4 fp32 acc

__device__ __forceinline__ float b2f(unsigned short u) {
    union { unsigned int i; float f; } v; v.i = ((unsigned int)u) << 16; return v.f;
}
__device__ __forceinline__ unsigned short f2b(float f) {   // fp32 -> bf16 RNE
    unsigned int x = __float_as_uint(f);
    x += 0x7fffu + ((x >> 16) & 1u);
    return (unsigned short)(x >> 16);
}
// int64 layout sniff (odd int32 words all zero) — insurance, contract says int32
__device__ __forceinline__ bool ht_is_i64(const int* __restrict__ ht) {
    int o = 0;
    #pragma unroll
    for (int k = 1; k < 16; k += 2) o |= ht[k];
    return o == 0;
}
__device__ __forceinline__ int clampN(int v) {
    unsigned u = (unsigned)v;
    return (u < N_NODES) ? v : 0;
}

// ---- fp32 -> bf16: H -> Hbf; Wf|Wb -> Wcat (256 rows x 1024 k) -------------
__global__ __launch_bounds__(256) void convert_kernel(
    const float* __restrict__ H, const float* __restrict__ Wf,
    const float* __restrict__ Wb,
    unsigned short* __restrict__ Hbf, unsigned short* __restrict__ Wcat)
{
    constexpr int NH4 = (N_NODES * EMBED) / 4;     // 2,560,000
    constexpr int NW4 = (EMBED * 2 * EMBED) / 4;   // 32,768 per W
    int ci = blockIdx.x * 256 + threadIdx.x;
    const float* src; unsigned short* dst;
    if (ci < NH4) {
        src = &H[(size_t)ci * 4]; dst = &Hbf[(size_t)ci * 4];
    } else if (ci < NH4 + NW4) {
        int j = (ci - NH4) * 4; int n = j >> 9, k = j & 511;
        src = &Wf[j]; dst = &Wcat[(size_t)n * 1024 + k];
    } else if (ci < NH4 + 2 * NW4) {
        int j = (ci - NH4 - NW4) * 4; int n = j >> 9, k = j & 511;
        src = &Wb[j]; dst = &Wcat[(size_t)n * 1024 + 512 + k];
    } else return;
    float4 v = *(const float4*)src;
    ushort4 o; o.x = f2b(v.x); o.y = f2b(v.y); o.z = f2b(v.z); o.w = f2b(v.w);
    *(ushort4*)dst = o;
}

// ---- build padded per-node edge lists (fwd keyed by tail, back by head) ----
__global__ __launch_bounds__(256) void build_kernel(
    const int* __restrict__ ht,
    int* __restrict__ cntf, int* __restrict__ cntb,
    int* __restrict__ listf, int* __restrict__ listb)
{
    int e = blockIdx.x * 256 + threadIdx.x;
    if (e >= N_EDGES) return;
    const bool wide = ht_is_i64(ht);
    int head = clampN(wide ? ht[(size_t)4 * e]     : ht[2 * e]);
    int tail = clampN(wide ? ht[(size_t)4 * e + 2] : ht[2 * e + 1]);
    int pf = atomicAdd(&cntf[tail], 1);
    if (pf < CAP) listf[tail * CAP + pf] = e;
    int pb = atomicAdd(&cntb[head], 1);
    if (pb < CAP) listb[head * CAP + pb] = e;
}

// ---- fused: gather-sum S (LDS, bf16) -> GEMM vs Wcat -> bias/mean/leaky/
// ---- residual/LayerNorm -> out. Block = 16 nodes, 512 thr (8 waves),
// ---- 2 nodes per wave. launch_bounds(512,4): 128-VGPR budget (no spill)
// ---- -> ~16 waves/CU. Dual-node interleaved 4+4 edge groups keep 16 loads
// ---- in flight per wave (R1's proven depth) with more resident waves.
__global__ __launch_bounds__(512, 4) void fused_kernel(
    const unsigned short* __restrict__ Hbf, const float* __restrict__ E,
    const int* __restrict__ ht, const unsigned short* __restrict__ Wcat,
    const float* __restrict__ bf_, const float* __restrict__ bb_,
    const float* __restrict__ H, const float* __restrict__ lw,
    const float* __restrict__ lb,
    const int* __restrict__ cntf, const int* __restrict__ cntb,
    const int* __restrict__ listf, const int* __restrict__ listb,
    float* __restrict__ out)
{
    constexpr int LDK = 1032;                 // 1024 + 8 pad (keeps 16B align)
    __shared__ unsigned short S[16 * LDK];    // 33 KB
    __shared__ float stats[16][8][2];         // per-row per-wave (s, ss)

    const int tid  = threadIdx.x;
    const int wid  = tid >> 6;                // 0..7
    const int lane = tid & 63;
    const int q    = lane >> 4;
    const int c    = lane & 15;
    const int m0   = blockIdx.x * 16;
    const bool wide = ht_is_i64(ht);
    const int loff = lane * 4;

    // ---- hoisted preloads: counts + edge lists + neighbor ids, 2 nodes ----
    const int node0 = m0 + wid * 2, node1 = node0 + 1;
    int c0f = min(cntf[node0], CAP), c1f = min(cntf[node1], CAP);
    int c0b = min(cntb[node0], CAP), c1b = min(cntb[node1], CAP);
    int e0f = (lane < c0f) ? listf[node0 * CAP + lane] : 0;
    int e1f = (lane < c1f) ? listf[node1 * CAP + lane] : 0;
    int e0b = (lane < c0b) ? listb[node0 * CAP + lane] : 0;
    int e1b = (lane < c1b) ? listb[node1 * CAP + lane] : 0;
    int n0f = clampN(wide ? ht[(size_t)4 * e0f]     : ht[2 * e0f]);      // head
    int n1f = clampN(wide ? ht[(size_t)4 * e1f]     : ht[2 * e1f]);
    int n0b = clampN(wide ? ht[(size_t)4 * e0b + 2] : ht[2 * e0b + 1]);  // tail
    int n1b = clampN(wide ? ht[(size_t)4 * e1b + 2] : ht[2 * e1b + 1]);

    const int nf0 = __builtin_amdgcn_readfirstlane(c0f);
    const int nf1 = __builtin_amdgcn_readfirstlane(c1f);
    const int nb0 = __builtin_amdgcn_readfirstlane(c0b);
    const int nb1 = __builtin_amdgcn_readfirstlane(c1b);

    float aH0f[4] = {0,0,0,0}, aE0f[4] = {0,0,0,0};
    float aH1f[4] = {0,0,0,0}, aE1f[4] = {0,0,0,0};
    float aH0b[4] = {0,0,0,0}, aE0b[4] = {0,0,0,0};
    float aH1b[4] = {0,0,0,0}, aE1b[4] = {0,0,0,0};

    // ---- fwd direction: 4 edges node0 + 4 edges node1 per group (16 loads)
    {
        const int nm = (nf0 > nf1) ? nf0 : nf1;
        for (int t = 0; t < nm; t += 4) {
            float4 ea[4], eb[4]; ushort4 ha[4], hb[4];
            #pragma unroll
            for (int u = 0; u < 4; u++) {
                const int ea_ = __builtin_amdgcn_readlane(e0f, t + u);
                const int na_ = __builtin_amdgcn_readlane(n0f, t + u);
                const int eb_ = __builtin_amdgcn_readlane(e1f, t + u);
                const int nb_ = __builtin_amdgcn_readlane(n1f, t + u);
                ea[u] = *(const float4*)(&E[(size_t)ea_ * EMBED + loff]);
                ha[u] = *(const ushort4*)(&Hbf[(size_t)na_ * EMBED + loff]);
                eb[u] = *(const float4*)(&E[(size_t)eb_ * EMBED + loff]);
                hb[u] = *(const ushort4*)(&Hbf[(size_t)nb_ * EMBED + loff]);
            }
            #pragma unroll
            for (int u = 0; u < 4; u++) {
                const float w0 = (t + u < nf0) ? 1.0f : 0.0f;
                const float w1 = (t + u < nf1) ? 1.0f : 0.0f;
                aE0f[0] += w0 * ea[u].x; aE0f[1] += w0 * ea[u].y;
                aE0f[2] += w0 * ea[u].z; aE0f[3] += w0 * ea[u].w;
                aH0f[0] += w0 * b2f(ha[u].x); aH0f[1] += w0 * b2f(ha[u].y);
                aH0f[2] += w0 * b2f(ha[u].z); aH0f[3] += w0 * b2f(ha[u].w);
                aE1f[0] += w1 * eb[u].x; aE1f[1] += w1 * eb[u].y;
                aE1f[2] += w1 * eb[u].z; aE1f[3] += w1 * eb[u].w;
                aH1f[0] += w1 * b2f(hb[u].x); aH1f[1] += w1 * b2f(hb[u].y);
                aH1f[2] += w1 * b2f(hb[u].z); aH1f[3] += w1 * b2f(hb[u].w);
            }
        }
    }
    // ---- back direction --------------------------------------------------
    {
        const int nm = (nb0 > nb1) ? nb0 : nb1;
        for (int t = 0; t < nm; t += 4) {
            float4 ea[4], eb[4]; ushort4 ha[4], hb[4];
            #pragma unroll
            for (int u = 0; u < 4; u++) {
                const int ea_ = __builtin_amdgcn_readlane(e0b, t + u);
                const int na_ = __builtin_amdgcn_readlane(n0b, t + u);
                const int eb_ = __builtin_amdgcn_readlane(e1b, t + u);
                const int nb_ = __builtin_amdgcn_readlane(n1b, t + u);
                ea[u] = *(const float4*)(&E[(size_t)ea_ * EMBED + loff]);
                ha[u] = *(const ushort4*)(&Hbf[(size_t)na_ * EMBED + loff]);
                eb[u] = *(const float4*)(&E[(size_t)eb_ * EMBED + loff]);
                hb[u] = *(const ushort4*)(&Hbf[(size_t)nb_ * EMBED + loff]);
            }
            #pragma unroll
            for (int u = 0; u < 4; u++) {
                const float w0 = (t + u < nb0) ? 1.0f : 0.0f;
                const float w1 = (t + u < nb1) ? 1.0f : 0.0f;
                aE0b[0] += w0 * ea[u].x; aE0b[1] += w0 * ea[u].y;
                aE0b[2] += w0 * ea[u].z; aE0b[3] += w0 * ea[u].w;
                aH0b[0] += w0 * b2f(ha[u].x); aH0b[1] += w0 * b2f(ha[u].y);
                aH0b[2] += w0 * b2f(ha[u].z); aH0b[3] += w0 * b2f(ha[u].w);
                aE1b[0] += w1 * eb[u].x; aE1b[1] += w1 * eb[u].y;
                aE1b[2] += w1 * eb[u].z; aE1b[3] += w1 * eb[u].w;
                aH1b[0] += w1 * b2f(hb[u].x); aH1b[1] += w1 * b2f(hb[u].y);
                aH1b[2] += w1 * b2f(hb[u].z); aH1b[3] += w1 * b2f(hb[u].w);
            }
        }
    }

    // ---- S rows = [ΣH_head | ΣE_fwd | ΣH_tail | ΣE_back] as bf16 ----------
    {
        const int r0 = wid * 2, r1 = r0 + 1;
        ushort4 o;
        o.x=f2b(aH0f[0]); o.y=f2b(aH0f[1]); o.z=f2b(aH0f[2]); o.w=f2b(aH0f[3]);
        *(ushort4*)(&S[r0 * LDK +   0 + loff]) = o;
        o.x=f2b(aE0f[0]); o.y=f2b(aE0f[1]); o.z=f2b(aE0f[2]); o.w=f2b(aE0f[3]);
        *(ushort4*)(&S[r0 * LDK + 256 + loff]) = o;
        o.x=f2b(aH0b[0]); o.y=f2b(aH0b[1]); o.z=f2b(aH0b[2]); o.w=f2b(aH0b[3]);
        *(ushort4*)(&S[r0 * LDK + 512 + loff]) = o;
        o.x=f2b(aE0b[0]); o.y=f2b(aE0b[1]); o.z=f2b(aE0b[2]); o.w=f2b(aE0b[3]);
        *(ushort4*)(&S[r0 * LDK + 768 + loff]) = o;
        o.x=f2b(aH1f[0]); o.y=f2b(aH1f[1]); o.z=f2b(aH1f[2]); o.w=f2b(aH1f[3]);
        *(ushort4*)(&S[r1 * LDK +   0 + loff]) = o;
        o.x=f2b(aE1f[0]); o.y=f2b(aE1f[1]); o.z=f2b(aE1f[2]); o.w=f2b(aE1f[3]);
        *(ushort4*)(&S[r1 * LDK + 256 + loff]) = o;
        o.x=f2b(aH1b[0]); o.y=f2b(aH1b[1]); o.z=f2b(aH1b[2]); o.w=f2b(aH1b[3]);
        *(ushort4*)(&S[r1 * LDK + 512 + loff]) = o;
        o.x=f2b(aE1b[0]); o.y=f2b(aE1b[1]); o.z=f2b(aE1b[2]); o.w=f2b(aE1b[3]);
        *(ushort4*)(&S[r1 * LDK + 768 + loff]) = o;
    }
    __syncthreads();

    // ---- GEMM: 16 x 1024 x 256, wave covers cols n0..n0+31 ----------------
    const int n0 = wid * 32;
    f32x4 acc[2];
    #pragma unroll
    for (int nt = 0; nt < 2; nt++) acc[nt] = (f32x4){0.f,0.f,0.f,0.f};

    #pragma unroll 4
    for (int k0 = 0; k0 < 1024; k0 += 32) {
        // A frag: A[m=c][k=q*8+j]
        s16x8 a = *(const s16x8*)(&S[c * LDK + k0 + q * 8]);
        #pragma unroll
        for (int nt = 0; nt < 2; nt++) {
            s16x8 b = *(const s16x8*)(&Wcat[(size_t)(n0 + nt * 16 + c) * 1024 + k0 + q * 8]);
            acc[nt] = __builtin_amdgcn_mfma_f32_16x16x32_bf16(a, b, acc[nt], 0, 0, 0);
        }
    }

    // ---- epilogue: bias, /count, leaky, +H, LayerNorm ----------------------
    float x[4][2];                 // [reg(row)][nt]
    float sr[4], ssr[4];
    #pragma unroll
    for (int reg = 0; reg < 4; reg++) {
        const int row  = q * 4 + reg;
        const int node = m0 + row;
        const float cf = (float)cntf[node];
        const float cb = (float)cntb[node];
        const float tot = cf + cb;
        const float inv = (tot > 0.f) ? (1.0f / tot) : 0.f;
        float s = 0.f, ss = 0.f;
        #pragma unroll
        for (int nt = 0; nt < 2; nt++) {
            const int j = n0 + nt * 16 + c;
            float v = acc[nt][reg] + cf * bf_[j] + cb * bb_[j];
            float m = v * inv;
            m = (m > 0.f) ? m : 0.01f * m;          // leaky_relu
            float xx = m + H[(size_t)node * EMBED + j];
            x[reg][nt] = xx; s += xx; ss += xx * xx;
        }
        sr[reg] = s; ssr[reg] = ss;
    }
    // reduce over the 16 c-lanes within each quad
    #pragma unroll
    for (int off = 1; off < 16; off <<= 1) {
        #pragma unroll
        for (int reg = 0; reg < 4; reg++) {
            sr[reg]  += __shfl_xor(sr[reg],  off);
            ssr[reg] += __shfl_xor(ssr[reg], off);
        }
    }
    if (c == 0) {
        #pragma unroll
        for (int reg = 0; reg < 4; reg++) {
            stats[q * 4 + reg][wid][0] = sr[reg];
            stats[q * 4 + reg][wid][1] = ssr[reg];
        }
    }
    __syncthreads();
    #pragma unroll
    for (int reg = 0; reg < 4; reg++) {
        const int row  = q * 4 + reg;
        const int node = m0 + row;
        float s = 0.f, ss = 0.f;
        #pragma unroll
        for (int w8 = 0; w8 < 8; w8++) {
            s  += stats[row][w8][0];
            ss += stats[row][w8][1];
        }
        const float mean = s * (1.0f / EMBED);
        float var = ss * (1.0f / EMBED) - mean * mean;
        var = var < 0.f ? 0.f : var;
        const float rstd = rsqrtf(var + 1e-5f);
        #pragma unroll
        for (int nt = 0; nt < 2; nt++) {
            const int j = n0 + nt * 16 + c;
            out[(size_t)node * EMBED + j] = (x[reg][nt] - mean) * rstd * lw[j] + lb[j];
        }
    }
}

extern "C" void kernel_launch(void* const* d_in, const int* in_sizes, int n_in,
                              void* d_out, int out_size, void* d_ws, size_t ws_size,
                              hipStream_t stream) {
    const float* H   = (const float*)d_in[0];
    const float* E   = (const float*)d_in[1];
    const int*   ht  = (const int*)d_in[2];
    const float* Wf  = (const float*)d_in[5];
    const float* bf_ = (const float*)d_in[6];
    const float* Wb  = (const float*)d_in[7];
    const float* bb_ = (const float*)d_in[8];
    const float* lw  = (const float*)d_in[9];
    const float* lb  = (const float*)d_in[10];
    float* out = (float*)d_out;

    // ws layout (~42 MB total)
    int* cntf  = (int*)d_ws;                       // 40960 ints
    int* cntb  = cntf + 40960;
    int* listf = cntb + 40960;                     // 40000*CAP ints
    int* listb = listf + N_NODES * CAP;
    unsigned short* Hbf  = (unsigned short*)(listb + N_NODES * CAP);  // 10.24M
    unsigned short* Wcat = Hbf + (size_t)N_NODES * EMBED;             // 262144

    hipMemsetAsync(d_ws, 0, 2 * 40960 * sizeof(int), stream);

    constexpr int NCHUNK = (N_NODES * EMBED + 2 * EMBED * 2 * EMBED) / 4;
    convert_kernel<<<(NCHUNK + 255) / 256, 256, 0, stream>>>(H, Wf, Wb, Hbf, Wcat);
    build_kernel<<<(N_EDGES + 255) / 256, 256, 0, stream>>>(ht, cntf, cntb, listf, listb);
    fused_kernel<<<N_NODES / 16, 512, 0, stream>>>(Hbf, E, ht, Wcat, bf_, bb_,
                                                   H, lw, lb, cntf, cntb,
                                                   listf, listb, out);
}